// Round 6
// baseline (199.344 us; speedup 1.0000x reference)
//
#include <hip/hip_runtime.h>

#define EPSF 1e-20f

typedef float v2f __attribute__((ext_vector_type(2)));
typedef float v4f __attribute__((ext_vector_type(4)));

constexpr int B_ = 2, C_ = 32, O_ = 32, H_ = 256, W_ = 512;
constexpr int HO = 254, WO = 510;
constexpr int HW  = H_ * W_;        // 131072
constexpr int PLO = HO * WO;        // 129540
constexpr int OUT1 = B_ * O_ * PLO;
constexpr int IMG  = B_ * C_ * HW;  // 8,388,608
constexpr int WT2  = 128;           // K2 tile width (pixels per block)
constexpr int ABS_ = 68;            // AB row stride in floats (16B-aligned rows)

__device__ __forceinline__ float sp_(float x) { return log1pf(expf(x)); }
__device__ __forceinline__ float rcp_(float x) { return __builtin_amdgcn_rcpf(x); }

// pack two floats as bf16(RN) into one uint: low16 = g, high16 = c
__device__ __forceinline__ unsigned bfpack(float g, float c) {
  unsigned ug = __float_as_uint(g);
  unsigned uc = __float_as_uint(c);
  ug = ug + 0x7FFFu + ((ug >> 16) & 1u);
  uc = uc + 0x7FFFu + ((uc >> 16) & 1u);
  return (ug >> 16) | (uc & 0xFFFF0000u);
}
__device__ __forceinline__ float bf_lo(unsigned u) { return __uint_as_float(u << 16); }
__device__ __forceinline__ float bf_hi(unsigned u) { return __uint_as_float(u & 0xFFFF0000u); }

// ---------------------------------------------------------------------------
// Setup: softplus weights + reductions into params.
// Layout (floats): [0]=w [1]=sum(sw) [2]=sum(cw)
//   [16..304)   = sw[c][k]           (C*9)
//   [304..1328) = cwT[c][o]          (transposed)
// ---------------------------------------------------------------------------
__global__ __launch_bounds__(256) void k_setup(const float* __restrict__ w_prop,
                                               const float* __restrict__ spw,
                                               const float* __restrict__ chw,
                                               float* __restrict__ params) {
  __shared__ float red[256];
  int t = threadIdx.x;
  float l1 = 0.f;
  for (int i = t; i < 288; i += 256) { float v = sp_(spw[i]); params[16 + i] = v; l1 += v; }
  red[t] = l1; __syncthreads();
  for (int k = 128; k > 0; k >>= 1) { if (t < k) red[t] += red[t + k]; __syncthreads(); }
  float SW = red[0]; __syncthreads();
  float l2 = 0.f;
  for (int i = t; i < 1024; i += 256) {
    int o = i >> 5, c = i & 31;
    float v = sp_(chw[o * C_ + c]);
    params[304 + c * O_ + o] = v;
    l2 += v;
  }
  red[t] = l2; __syncthreads();
  for (int k = 128; k > 0; k >>= 1) { if (t < k) red[t] += red[t + k]; __syncthreads(); }
  if (t == 0) { params[0] = sp_(w_prop[0]); params[1] = SW; params[2] = red[0]; }
}

// ---------------------------------------------------------------------------
// K1: per-pixel vertical fusion -> packed bf16 (gy_f, cgy_f). Pure streaming.
// ---------------------------------------------------------------------------
__global__ __launch_bounds__(256) void k1_gyf(const float* __restrict__ d,
                                              const float* __restrict__ cd,
                                              const float* __restrict__ s,
                                              const float* __restrict__ gy,
                                              const float* __restrict__ cgy,
                                              const float* __restrict__ params,
                                              unsigned* __restrict__ I) {
  const float w      = params[0];
  const float inv_w1 = rcp_(w + 1.0f);
  const int idx = blockIdx.x * 256 + threadIdx.x;
  const long i4 = (long)idx * 4;
  const int h = (int)((i4 >> 9) & (H_ - 1));
  const long up = (h == 0)      ? i4 + (long)(H_ - 1) * W_ : i4 - W_;
  const long dn = (h == H_ - 1) ? i4 - (long)(H_ - 1) * W_ : i4 + W_;

  float4 duv = *(const float4*)(d + up);
  float4 ddv = *(const float4*)(d + dn);
  float4 sv  = *(const float4*)(s + i4);
  float4 suv = *(const float4*)(s + up);
  float4 sdv = *(const float4*)(s + dn);
  float4 cduv = (h == 0)      ? make_float4(0.f, 0.f, 0.f, 0.f) : *(const float4*)(cd + up);
  float4 cddv = (h == H_ - 1) ? make_float4(0.f, 0.f, 0.f, 0.f) : *(const float4*)(cd + dn);
  float4 gyv  = *(const float4*)(gy + i4);
  float4 cgyv = *(const float4*)(cgy + i4);

  const float* pdu = (const float*)&duv;  const float* pdd = (const float*)&ddv;
  const float* ps  = (const float*)&sv;   const float* psu = (const float*)&suv;
  const float* psd = (const float*)&sdv;  const float* pcu = (const float*)&cduv;
  const float* pcd = (const float*)&cddv; const float* pg  = (const float*)&gyv;
  const float* pc  = (const float*)&cgyv;

  uint4 o;
  unsigned* po = (unsigned*)&o;
#pragma unroll
  for (int j = 0; j < 4; ++j) {
    const float cu = pcu[j], cdn = pcd[j];
    const float cfd = ps[j] * psu[j] * psd[j] * cu * cu;           // cd_up twice (faithful)
    const float height = (cu * pdu[j] + cdn * pdd[j]) * rcp_(cu + cdn + EPSF);
    const float gfd = (pdd[j] - pdu[j]) * 0.5f * rcp_(height + EPSF);
    const float a = w * pc[j];
    const float vg = (a * pg[j] + cfd * gfd) * rcp_(a + cfd + EPSF);
    const float vc = (a + cfd) * inv_w1;
    po[j] = bfpack(vg, vc);
  }
  *(uint4*)(I + i4) = o;
}

// ---------------------------------------------------------------------------
// K2: fused 3x3 grouped conv + 1x1 channel mix. Tile = (b, ho, 128 px).
// Phase A: wave = channel-group (8 ch), lane = pixel-pair; 1-ch-ahead
//          load/compute pipeline; all weights via wave-uniform s_loads.
// Phase B: lane = px (x2), wave = o-group of 8; ds_read_b128 over AB[px][c].
// ---------------------------------------------------------------------------
struct Ch { uint2 r[3][2]; v2f sp[9]; };

__global__ __launch_bounds__(256, 4) void k2_fused(const unsigned* __restrict__ I,
                                                   const float* __restrict__ spr,
                                                   const float* __restrict__ params,
                                                   const float* __restrict__ bias,
                                                   float* __restrict__ out) {
  __shared__ float AB[WT2][ABS_];   // [px][2c+(0:g,1:c)], 272B rows (16B aligned)

  const int b   = blockIdx.z;
  const int ho  = blockIdx.y;
  const int wo0 = blockIdx.x * WT2;
  const int t   = threadIdx.x;

  const float invSW = rcp_(params[1]);
  const float invCW = rcp_(params[2]);

  // ---- Phase A ----
  const int pp  = t & 63;                                     // pixel pair
  const int cg  = __builtin_amdgcn_readfirstlane(t >> 6);     // 0..3 wave-uniform
  const int wo  = wo0 + 2 * pp;
  const int wos = (wo <= WO - 2) ? wo : (WO - 2);
  const int c0  = cg * 8;

  const unsigned* Ibase = I + (b * C_ + c0) * HW + ho * W_ + wos;
  const float*    Sbase = spr + (long)(b * C_ + c0) * 9 * PLO + ho * WO + wos;

  auto loadc = [&](int ci, Ch& L) {
    const unsigned* Ip = Ibase + ci * HW;
#pragma unroll
    for (int i = 0; i < 3; ++i) {
      L.r[i][0] = *(const uint2*)(Ip + i * W_);
      L.r[i][1] = *(const uint2*)(Ip + i * W_ + 2);
    }
    const float* sp = Sbase + (long)ci * 9 * PLO;
#pragma unroll
    for (int k = 0; k < 9; ++k) L.sp[k] = *(const v2f*)(sp + (long)k * PLO);
  };

  auto computec = [&](int ci, const Ch& L) {
    float gf[3][4], cf[3][4];
#pragma unroll
    for (int i = 0; i < 3; ++i) {
      const unsigned uu[4] = {L.r[i][0].x, L.r[i][0].y, L.r[i][1].x, L.r[i][1].y};
#pragma unroll
      for (int j = 0; j < 4; ++j) { gf[i][j] = bf_lo(uu[j]); cf[i][j] = bf_hi(uu[j]); }
    }
    const float* swc = params + 16 + (c0 + ci) * 9;   // uniform -> s_load
#pragma unroll
    for (int u = 0; u < 2; ++u) {
      float nom = 0.f, den = 0.f;
#pragma unroll
      for (int i = 0; i < 3; ++i)
#pragma unroll
        for (int j = 0; j < 3; ++j) {
          const float cp = cf[i][u + j] * L.sp[i * 3 + j][u] * swc[i * 3 + j];
          nom += cp * gf[i][u + j];
          den += cp;
        }
      const float gy_sp  = nom * rcp_(den + EPSF);
      const float cgy_sp = den * invSW;
      *(v2f*)&AB[2 * pp + u][2 * (c0 + ci)] = (v2f){gy_sp * cgy_sp, cgy_sp};
    }
  };

  {
    Ch Ca, Cb;
    loadc(0, Ca);
    loadc(1, Cb);
    computec(0, Ca);
    loadc(2, Ca);
    computec(1, Cb);
    loadc(3, Cb);
    computec(2, Ca);
    loadc(4, Ca);
    computec(3, Cb);
    loadc(5, Cb);
    computec(4, Ca);
    loadc(6, Ca);
    computec(5, Cb);
    loadc(7, Cb);
    computec(6, Ca);
    computec(7, Cb);
  }
  __syncthreads();

  // ---- Phase B ----
  const int px0 = t & 63;                                      // wo0+px0 <= 447 < WO always
  const int px1 = px0 + 64;
  const int ogr = __builtin_amdgcn_readfirstlane(t >> 6);      // 0..3 wave-uniform
  const float* cwT = params + 304;

  v2f acc0[8], acc1[8];
#pragma unroll
  for (int oj = 0; oj < 8; ++oj) { acc0[oj] = (v2f){0.f, 0.f}; acc1[oj] = (v2f){0.f, 0.f}; }

#pragma unroll
  for (int c2 = 0; c2 < C_; c2 += 2) {
    const v4f a0 = *(const v4f*)&AB[px0][2 * c2];   // ch c2, c2+1 for px0
    const v4f a1 = *(const v4f*)&AB[px1][2 * c2];
    const float* w0 = cwT + c2 * O_ + ogr * 8;      // uniform -> s_load_dwordx8
    const float* w1 = w0 + O_;
    const v2f g00 = (v2f){a0.x, a0.y}, g01 = (v2f){a0.z, a0.w};
    const v2f g10 = (v2f){a1.x, a1.y}, g11 = (v2f){a1.z, a1.w};
#pragma unroll
    for (int oj = 0; oj < 8; ++oj) {
      acc0[oj] += g00 * w0[oj];
      acc0[oj] += g01 * w1[oj];
      acc1[oj] += g10 * w0[oj];
      acc1[oj] += g11 * w1[oj];
    }
  }

  const int  wob1 = wo0 + px1;
  const long ob   = (long)b * O_ * PLO + (long)ho * WO + wo0;
#pragma unroll
  for (int oj = 0; oj < 8; ++oj) {
    const int o = ogr * 8 + oj;
    const float bv = bias[o];                        // uniform -> s_load
    out[ob + (long)o * PLO + px0]        = acc0[oj].x * rcp_(acc0[oj].y + EPSF) + bv;
    out[OUT1 + ob + (long)o * PLO + px0] = acc0[oj].y * invCW;
    if (wob1 < WO) {
      out[ob + (long)o * PLO + px1]        = acc1[oj].x * rcp_(acc1[oj].y + EPSF) + bv;
      out[OUT1 + ob + (long)o * PLO + px1] = acc1[oj].y * invCW;
    }
  }
}

// ---------------------------------------------------------------------------
extern "C" void kernel_launch(void* const* d_in, const int* in_sizes, int n_in,
                              void* d_out, int out_size, void* d_ws, size_t ws_size,
                              hipStream_t stream) {
  const float* d      = (const float*)d_in[0];
  const float* cd     = (const float*)d_in[1];
  const float* s      = (const float*)d_in[2];
  // d_in[3]=cs, d_in[4]=gx, d_in[5]=cgx unused by the reference
  const float* gy     = (const float*)d_in[6];
  const float* cgy    = (const float*)d_in[7];
  const float* spr    = (const float*)d_in[8];
  const float* w_prop = (const float*)d_in[9];
  const float* spw    = (const float*)d_in[10];
  const float* chw    = (const float*)d_in[11];
  const float* bias   = (const float*)d_in[12];
  float* out = (float*)d_out;

  float* params = (float*)d_ws;                 // 4096 floats reserved
  unsigned* I   = (unsigned*)d_ws + 4096;       // packed bf16 intermediate (33.5 MB)

  k_setup<<<1, 256, 0, stream>>>(w_prop, spw, chw, params);

  k1_gyf<<<IMG / 4 / 256, 256, 0, stream>>>(d, cd, s, gy, cgy, params, I);

  dim3 g2(WT2 == 128 ? 4 : 8, HO, B_);   // (4, 254, 2) = 2032 blocks
  k2_fused<<<g2, 256, 0, stream>>>(I, spr, params, bias, out);
}

// Round 7
// 147.960 us; speedup vs baseline: 1.3473x; 1.3473x over previous
//
#include <hip/hip_runtime.h>

#define EPSF 1e-20f

typedef float v2f __attribute__((ext_vector_type(2)));

constexpr int B_ = 2, C_ = 32, O_ = 32, H_ = 256, W_ = 512;
constexpr int HO = 254, WO = 510;
constexpr int HW  = H_ * W_;        // 131072
constexpr int PLO = HO * WO;        // 129540
constexpr int OUT1 = B_ * O_ * PLO;
constexpr int IMG  = B_ * C_ * HW;  // 8,388,608
constexpr int WT2  = 64;            // K2 tile width (pixels per block)

__device__ __forceinline__ float sp_(float x) { return log1pf(expf(x)); }
__device__ __forceinline__ float rcp_(float x) { return __builtin_amdgcn_rcpf(x); }

// pack two floats as bf16(RN) into one uint: low16 = g, high16 = c
__device__ __forceinline__ unsigned bfpack(float g, float c) {
  unsigned ug = __float_as_uint(g);
  unsigned uc = __float_as_uint(c);
  ug = ug + 0x7FFFu + ((ug >> 16) & 1u);
  uc = uc + 0x7FFFu + ((uc >> 16) & 1u);
  return (ug >> 16) | (uc & 0xFFFF0000u);
}
__device__ __forceinline__ float bf_lo(unsigned u) { return __uint_as_float(u << 16); }
__device__ __forceinline__ float bf_hi(unsigned u) { return __uint_as_float(u & 0xFFFF0000u); }

// ---------------------------------------------------------------------------
// Setup: softplus weights + reductions into params.
// Layout (floats): [0]=w [1]=sum(sw) [2]=sum(cw)
//   [16..304)   = sw[c][k]           (C*9)
//   [304..1328) = cwT[c][o]          (transposed: cwT[c*32+o] = softplus(chw[o*32+c]))
// ---------------------------------------------------------------------------
__global__ __launch_bounds__(256) void k_setup(const float* __restrict__ w_prop,
                                               const float* __restrict__ spw,
                                               const float* __restrict__ chw,
                                               float* __restrict__ params) {
  __shared__ float red[256];
  int t = threadIdx.x;
  float l1 = 0.f;
  for (int i = t; i < 288; i += 256) { float v = sp_(spw[i]); params[16 + i] = v; l1 += v; }
  red[t] = l1; __syncthreads();
  for (int k = 128; k > 0; k >>= 1) { if (t < k) red[t] += red[t + k]; __syncthreads(); }
  float SW = red[0]; __syncthreads();
  float l2 = 0.f;
  for (int i = t; i < 1024; i += 256) {
    int o = i >> 5, c = i & 31;
    float v = sp_(chw[o * C_ + c]);
    params[304 + c * O_ + o] = v;
    l2 += v;
  }
  red[t] = l2; __syncthreads();
  for (int k = 128; k > 0; k >>= 1) { if (t < k) red[t] += red[t + k]; __syncthreads(); }
  if (t == 0) { params[0] = sp_(w_prop[0]); params[1] = SW; params[2] = red[0]; }
}

// ---------------------------------------------------------------------------
// K1: per-pixel vertical fusion -> packed bf16 (gy_f, cgy_f), float4 in,
// uint4 out. Pure streaming, no barriers.
// ---------------------------------------------------------------------------
__global__ __launch_bounds__(256) void k1_gyf(const float* __restrict__ d,
                                              const float* __restrict__ cd,
                                              const float* __restrict__ s,
                                              const float* __restrict__ gy,
                                              const float* __restrict__ cgy,
                                              const float* __restrict__ params,
                                              unsigned* __restrict__ I) {
  const float w      = params[0];
  const float inv_w1 = rcp_(w + 1.0f);
  const int idx = blockIdx.x * 256 + threadIdx.x;
  const long i4 = (long)idx * 4;
  const int h = (int)((i4 >> 9) & (H_ - 1));
  const long up = (h == 0)      ? i4 + (long)(H_ - 1) * W_ : i4 - W_;
  const long dn = (h == H_ - 1) ? i4 - (long)(H_ - 1) * W_ : i4 + W_;

  float4 duv = *(const float4*)(d + up);
  float4 ddv = *(const float4*)(d + dn);
  float4 sv  = *(const float4*)(s + i4);
  float4 suv = *(const float4*)(s + up);
  float4 sdv = *(const float4*)(s + dn);
  float4 cduv = (h == 0)      ? make_float4(0.f, 0.f, 0.f, 0.f) : *(const float4*)(cd + up);
  float4 cddv = (h == H_ - 1) ? make_float4(0.f, 0.f, 0.f, 0.f) : *(const float4*)(cd + dn);
  float4 gyv  = *(const float4*)(gy + i4);
  float4 cgyv = *(const float4*)(cgy + i4);

  const float* pdu = (const float*)&duv;  const float* pdd = (const float*)&ddv;
  const float* ps  = (const float*)&sv;   const float* psu = (const float*)&suv;
  const float* psd = (const float*)&sdv;  const float* pcu = (const float*)&cduv;
  const float* pcd = (const float*)&cddv; const float* pg  = (const float*)&gyv;
  const float* pc  = (const float*)&cgyv;

  uint4 o;
  unsigned* po = (unsigned*)&o;
#pragma unroll
  for (int j = 0; j < 4; ++j) {
    const float cu = pcu[j], cdn = pcd[j];
    const float cfd = ps[j] * psu[j] * psd[j] * cu * cu;           // cd_up twice (faithful)
    const float height = (cu * pdu[j] + cdn * pdd[j]) * rcp_(cu + cdn + EPSF);
    const float gfd = (pdd[j] - pdu[j]) * 0.5f * rcp_(height + EPSF);
    const float a = w * pc[j];
    const float vg = (a * pg[j] + cfd * gfd) * rcp_(a + cfd + EPSF);
    const float vc = (a + cfd) * inv_w1;
    po[j] = bfpack(vg, vc);
  }
  *(uint4*)(I + i4) = o;
}

// ---------------------------------------------------------------------------
// K2: fused 3x3 grouped conv + 1x1 channel mix (round-5 structure).
// Block = 256 threads = (b, ho, 64-wide wo tile). Grid (8, 254, 2) = 4064.
// Phase A: thread = (pixel-pair pp, channel-group cg of 4 channels);
//          DIVISION-FREE packed v2f conv: AB = (nom*invSW, den*invSW)
//          == (gy_sp*cgy_sp, cgy_sp) up to eps/den ~ 1e-20 relative.
// Phase B: thread = (px, o-group); ds_read_b64 + v_pk_fma channel mix;
//          weights via wave-uniform s_loads (cwT) and bias.
// ---------------------------------------------------------------------------
__global__ __launch_bounds__(256) void k2_fused(const unsigned* __restrict__ I,
                                                const float* __restrict__ spr,
                                                const float* __restrict__ params,
                                                const float* __restrict__ bias,
                                                float* __restrict__ out) {
  __shared__ float sw_s[288];
  __shared__ v2f AB[C_][WT2 + 2];   // [c][px], pad 2 -> 66 v2f per row

  const int b   = blockIdx.z;
  const int ho  = blockIdx.y;
  const int wo0 = blockIdx.x * WT2;
  const int t   = threadIdx.x;

  for (int i = t; i < 288; i += 256) sw_s[i] = params[16 + i];
  const float invSW = rcp_(params[1]);
  const float invCW = rcp_(params[2]);
  __syncthreads();

  // ---- Phase A ----
  const int pp = t & 31;         // pixel pair: px = 2pp, 2pp+1
  const int cg = t >> 5;         // 0..7 -> channels cg*4 .. cg*4+3
  const int wo  = wo0 + 2 * pp;
  const int wos = (wo <= WO - 2) ? wo : (WO - 2);   // even clamp (508)

#pragma unroll
  for (int ci = 0; ci < 4; ++ci) {
    const int c = cg * 4 + ci;
    const unsigned* Ip = I + (b * C_ + c) * HW + ho * W_ + wos;
    uint2 r0a = *(const uint2*)(Ip);
    uint2 r0b = *(const uint2*)(Ip + 2);
    uint2 r1a = *(const uint2*)(Ip + W_);
    uint2 r1b = *(const uint2*)(Ip + W_ + 2);
    uint2 r2a = *(const uint2*)(Ip + 2 * W_);
    uint2 r2b = *(const uint2*)(Ip + 2 * W_ + 2);

    const float* sp = spr + (long)(b * C_ + c) * 9 * PLO + ho * WO + wos;
    v2f spv[9];
#pragma unroll
    for (int k = 0; k < 9; ++k) spv[k] = *(const v2f*)(sp + (long)k * PLO);

    unsigned urow[3][4] = {{r0a.x, r0a.y, r0b.x, r0b.y},
                           {r1a.x, r1a.y, r1b.x, r1b.y},
                           {r2a.x, r2a.y, r2b.x, r2b.y}};
    float gf[3][4], cf[3][4];
#pragma unroll
    for (int i = 0; i < 3; ++i)
#pragma unroll
      for (int j = 0; j < 4; ++j) { gf[i][j] = bf_lo(urow[i][j]); cf[i][j] = bf_hi(urow[i][j]); }

    // packed conv over the pixel pair: nom/den as v2f (pixel u = component u)
    v2f nom = (v2f){0.f, 0.f};
    v2f den = (v2f){0.f, 0.f};
#pragma unroll
    for (int i = 0; i < 3; ++i) {
#pragma unroll
      for (int j = 0; j < 3; ++j) {
        const v2f cpair = (v2f){cf[i][j], cf[i][j + 1]};
        const v2f gpair = (v2f){gf[i][j], gf[i][j + 1]};
        v2f cp = cpair * spv[i * 3 + j];
        cp *= sw_s[c * 9 + i * 3 + j];
        nom += cp * gpair;     // v_pk_fma_f32
        den += cp;
      }
    }
    const v2f abg = nom * invSW;   // = gy_sp*cgy_sp (eps folded out)
    const v2f abc = den * invSW;   // = cgy_sp
    AB[c][2 * pp + 0] = (v2f){abg.x, abc.x};
    AB[c][2 * pp + 1] = (v2f){abg.y, abc.y};
  }
  __syncthreads();

  // ---- Phase B ----
  const int px  = t & 63;
  const int og  = __builtin_amdgcn_readfirstlane(t >> 6);  // 0..3, wave-uniform
  const int wob = wo0 + px;

  v2f ab[C_];
#pragma unroll
  for (int c = 0; c < C_; ++c) ab[c] = AB[c][px];

  const float* cwT = params + 304;     // [c][o], uniform indices -> s_load
  v2f acc[8];
#pragma unroll
  for (int oj = 0; oj < 8; ++oj) acc[oj] = (v2f){0.f, 0.f};
#pragma unroll
  for (int c = 0; c < C_; ++c) {
#pragma unroll
    for (int oj = 0; oj < 8; ++oj)
      acc[oj] += ab[c] * cwT[c * O_ + og * 8 + oj];   // v_pk_fma_f32
  }

  if (wob < WO) {
    const int obase = b * O_ * PLO + ho * WO + wob;
#pragma unroll
    for (int oj = 0; oj < 8; ++oj) {
      const int o = og * 8 + oj;
      out[obase + o * PLO]        = acc[oj].x * rcp_(acc[oj].y + EPSF) + bias[o];
      out[OUT1 + obase + o * PLO] = acc[oj].y * invCW;
    }
  }
}

// ---------------------------------------------------------------------------
extern "C" void kernel_launch(void* const* d_in, const int* in_sizes, int n_in,
                              void* d_out, int out_size, void* d_ws, size_t ws_size,
                              hipStream_t stream) {
  const float* d      = (const float*)d_in[0];
  const float* cd     = (const float*)d_in[1];
  const float* s      = (const float*)d_in[2];
  // d_in[3]=cs, d_in[4]=gx, d_in[5]=cgx unused by the reference
  const float* gy     = (const float*)d_in[6];
  const float* cgy    = (const float*)d_in[7];
  const float* spr    = (const float*)d_in[8];
  const float* w_prop = (const float*)d_in[9];
  const float* spw    = (const float*)d_in[10];
  const float* chw    = (const float*)d_in[11];
  const float* bias   = (const float*)d_in[12];
  float* out = (float*)d_out;

  float* params = (float*)d_ws;                       // 4096 floats reserved
  unsigned* I   = (unsigned*)d_ws + 4096;             // packed bf16 intermediate (33.5 MB)

  k_setup<<<1, 256, 0, stream>>>(w_prop, spw, chw, params);

  k1_gyf<<<IMG / 4 / 256, 256, 0, stream>>>(d, cd, s, gy, cgy, params, I);

  dim3 g2(8, HO, B_);   // (8, 254, 2) = 4064 blocks
  k2_fused<<<g2, 256, 0, stream>>>(I, spr, params, bias, out);
}

// Round 8
// 136.915 us; speedup vs baseline: 1.4560x; 1.0807x over previous
//
#include <hip/hip_runtime.h>

#define EPSF 1e-20f

typedef float v2f __attribute__((ext_vector_type(2)));

constexpr int B_ = 2, C_ = 32, O_ = 32, H_ = 256, W_ = 512;
constexpr int HO = 254, WO = 510;
constexpr int HW  = H_ * W_;        // 131072
constexpr int PLO = HO * WO;        // 129540
constexpr int OUT1 = B_ * O_ * PLO;
constexpr int IMG  = B_ * C_ * HW;  // 8,388,608
constexpr int WT2  = 128;           // K2 tile width (pixels per block)
constexpr int NB1  = IMG / 4 / 256; // 8192 streaming blocks in K1

__device__ __forceinline__ float sp_(float x) { return log1pf(expf(x)); }
__device__ __forceinline__ float rcp_(float x) { return __builtin_amdgcn_rcpf(x); }

// pack two floats as bf16(RN) into one uint: low16 = g, high16 = c
__device__ __forceinline__ unsigned bfpack(float g, float c) {
  unsigned ug = __float_as_uint(g);
  unsigned uc = __float_as_uint(c);
  ug = ug + 0x7FFFu + ((ug >> 16) & 1u);
  uc = uc + 0x7FFFu + ((uc >> 16) & 1u);
  return (ug >> 16) | (uc & 0xFFFF0000u);
}
__device__ __forceinline__ float bf_lo(unsigned u) { return __uint_as_float(u << 16); }
__device__ __forceinline__ float bf_hi(unsigned u) { return __uint_as_float(u & 0xFFFF0000u); }

// ---------------------------------------------------------------------------
// K1: per-pixel vertical fusion -> packed bf16 (gy_f, cgy_f). Pure streaming.
// Block NB1 (the extra last block) instead performs the weight setup:
//   params: [0]=w [1]=sum(sw) [2]=sum(cw) [16..304)=sw[c][k] [304..1328)=cwT[c][o]
// so the tiny setup runs concurrently with the streaming blocks.
// ---------------------------------------------------------------------------
__global__ __launch_bounds__(256) void k1_gyf(const float* __restrict__ d,
                                              const float* __restrict__ cd,
                                              const float* __restrict__ s,
                                              const float* __restrict__ gy,
                                              const float* __restrict__ cgy,
                                              const float* __restrict__ w_prop,
                                              const float* __restrict__ spw,
                                              const float* __restrict__ chw,
                                              float* __restrict__ params,
                                              unsigned* __restrict__ I) {
  __shared__ float red[256];
  const int t = threadIdx.x;

  if (blockIdx.x == NB1) {            // ---- setup block ----
    float l1 = 0.f;
    for (int i = t; i < 288; i += 256) { float v = sp_(spw[i]); params[16 + i] = v; l1 += v; }
    red[t] = l1; __syncthreads();
    for (int k = 128; k > 0; k >>= 1) { if (t < k) red[t] += red[t + k]; __syncthreads(); }
    float SW = red[0]; __syncthreads();
    float l2 = 0.f;
    for (int i = t; i < 1024; i += 256) {
      int o = i >> 5, c = i & 31;
      float v = sp_(chw[o * C_ + c]);
      params[304 + c * O_ + o] = v;   // transposed store
      l2 += v;
    }
    red[t] = l2; __syncthreads();
    for (int k = 128; k > 0; k >>= 1) { if (t < k) red[t] += red[t + k]; __syncthreads(); }
    if (t == 0) { params[0] = sp_(w_prop[0]); params[1] = SW; params[2] = red[0]; }
    return;
  }

  const float w      = sp_(w_prop[0]);   // computed inline (no params dependency)
  const float inv_w1 = rcp_(w + 1.0f);
  const int idx = blockIdx.x * 256 + t;
  const long i4 = (long)idx * 4;
  const int h = (int)((i4 >> 9) & (H_ - 1));
  const long up = (h == 0)      ? i4 + (long)(H_ - 1) * W_ : i4 - W_;
  const long dn = (h == H_ - 1) ? i4 - (long)(H_ - 1) * W_ : i4 + W_;

  float4 duv = *(const float4*)(d + up);
  float4 ddv = *(const float4*)(d + dn);
  float4 sv  = *(const float4*)(s + i4);
  float4 suv = *(const float4*)(s + up);
  float4 sdv = *(const float4*)(s + dn);
  float4 cduv = (h == 0)      ? make_float4(0.f, 0.f, 0.f, 0.f) : *(const float4*)(cd + up);
  float4 cddv = (h == H_ - 1) ? make_float4(0.f, 0.f, 0.f, 0.f) : *(const float4*)(cd + dn);
  float4 gyv  = *(const float4*)(gy + i4);
  float4 cgyv = *(const float4*)(cgy + i4);

  const float* pdu = (const float*)&duv;  const float* pdd = (const float*)&ddv;
  const float* ps  = (const float*)&sv;   const float* psu = (const float*)&suv;
  const float* psd = (const float*)&sdv;  const float* pcu = (const float*)&cduv;
  const float* pcd = (const float*)&cddv; const float* pg  = (const float*)&gyv;
  const float* pc  = (const float*)&cgyv;

  uint4 o;
  unsigned* po = (unsigned*)&o;
#pragma unroll
  for (int j = 0; j < 4; ++j) {
    const float cu = pcu[j], cdn = pcd[j];
    const float cfd = ps[j] * psu[j] * psd[j] * cu * cu;           // cd_up twice (faithful)
    const float height = (cu * pdu[j] + cdn * pdd[j]) * rcp_(cu + cdn + EPSF);
    const float gfd = (pdd[j] - pdu[j]) * 0.5f * rcp_(height + EPSF);
    const float a = w * pc[j];
    const float vg = (a * pg[j] + cfd * gfd) * rcp_(a + cfd + EPSF);
    const float vc = (a + cfd) * inv_w1;
    po[j] = bfpack(vg, vc);
  }
  *(uint4*)(I + i4) = o;
}

// ---------------------------------------------------------------------------
// K2: fused 3x3 grouped conv + 1x1 channel mix. 512 threads, 128-px tile.
// Phase A: wave = one channel-group of 4 channels (cg = t>>6 wave-uniform),
//          lane = pixel-pair -> every spr/I load is 512B wave-contiguous.
//          Division-free packed v2f conv: AB = (nom*invSW, den*invSW).
// Phase B: px = t&127, o-group = t>>7 (wave-uniform); ds_read_b64 +
//          v_pk_fma channel mix; weights via wave-uniform s_loads.
// ---------------------------------------------------------------------------
__global__ __launch_bounds__(512) void k2_fused(const unsigned* __restrict__ I,
                                                const float* __restrict__ spr,
                                                const float* __restrict__ params,
                                                const float* __restrict__ bias,
                                                float* __restrict__ out) {
  __shared__ float sw_s[288];
  __shared__ v2f AB[C_][WT2 + 2];   // [c][px], pad 2 -> 130 v2f per row

  const int b   = blockIdx.z;
  const int ho  = blockIdx.y;
  const int wo0 = blockIdx.x * WT2;
  const int t   = threadIdx.x;

  if (t < 288) sw_s[t] = params[16 + t];
  const float invSW = rcp_(params[1]);
  const float invCW = rcp_(params[2]);
  __syncthreads();

  // ---- Phase A ----
  const int pp = t & 63;                                     // pixel pair: px = 2pp, 2pp+1
  const int cg = __builtin_amdgcn_readfirstlane(t >> 6);     // 0..7, wave-uniform
  const int wo  = wo0 + 2 * pp;
  const int wos = (wo <= WO - 2) ? wo : (WO - 2);            // even clamp (508)

#pragma unroll
  for (int ci = 0; ci < 4; ++ci) {
    const int c = cg * 4 + ci;
    const unsigned* Ip = I + (b * C_ + c) * HW + ho * W_ + wos;
    uint2 r0a = *(const uint2*)(Ip);
    uint2 r0b = *(const uint2*)(Ip + 2);
    uint2 r1a = *(const uint2*)(Ip + W_);
    uint2 r1b = *(const uint2*)(Ip + W_ + 2);
    uint2 r2a = *(const uint2*)(Ip + 2 * W_);
    uint2 r2b = *(const uint2*)(Ip + 2 * W_ + 2);

    const float* sp = spr + (long)(b * C_ + c) * 9 * PLO + ho * WO + wos;
    v2f spv[9];
#pragma unroll
    for (int k = 0; k < 9; ++k) spv[k] = *(const v2f*)(sp + (long)k * PLO);

    unsigned urow[3][4] = {{r0a.x, r0a.y, r0b.x, r0b.y},
                           {r1a.x, r1a.y, r1b.x, r1b.y},
                           {r2a.x, r2a.y, r2b.x, r2b.y}};
    float gf[3][4], cf[3][4];
#pragma unroll
    for (int i = 0; i < 3; ++i)
#pragma unroll
      for (int j = 0; j < 4; ++j) { gf[i][j] = bf_lo(urow[i][j]); cf[i][j] = bf_hi(urow[i][j]); }

    // packed conv over the pixel pair: nom/den as v2f (pixel u = component u)
    v2f nom = (v2f){0.f, 0.f};
    v2f den = (v2f){0.f, 0.f};
#pragma unroll
    for (int i = 0; i < 3; ++i) {
#pragma unroll
      for (int j = 0; j < 3; ++j) {
        const v2f cpair = (v2f){cf[i][j], cf[i][j + 1]};
        const v2f gpair = (v2f){gf[i][j], gf[i][j + 1]};
        v2f cp = cpair * spv[i * 3 + j];
        cp *= sw_s[c * 9 + i * 3 + j];
        nom += cp * gpair;     // v_pk_fma_f32
        den += cp;
      }
    }
    const v2f abg = nom * invSW;   // = gy_sp*cgy_sp (eps folded out)
    const v2f abc = den * invSW;   // = cgy_sp
    AB[c][2 * pp + 0] = (v2f){abg.x, abc.x};
    AB[c][2 * pp + 1] = (v2f){abg.y, abc.y};
  }
  __syncthreads();

  // ---- Phase B ----
  const int px  = t & 127;
  const int og  = __builtin_amdgcn_readfirstlane(t >> 7);  // 0..3, wave-uniform
  const int wob = wo0 + px;

  v2f ab[C_];
#pragma unroll
  for (int c = 0; c < C_; ++c) ab[c] = AB[c][px];

  const float* cwT = params + 304;     // [c][o], uniform indices -> s_load
  v2f acc[8];
#pragma unroll
  for (int oj = 0; oj < 8; ++oj) acc[oj] = (v2f){0.f, 0.f};
#pragma unroll
  for (int c = 0; c < C_; ++c) {
#pragma unroll
    for (int oj = 0; oj < 8; ++oj)
      acc[oj] += ab[c] * cwT[c * O_ + og * 8 + oj];   // v_pk_fma_f32
  }

  if (wob < WO) {
    const int obase = b * O_ * PLO + ho * WO + wob;
#pragma unroll
    for (int oj = 0; oj < 8; ++oj) {
      const int o = og * 8 + oj;
      out[obase + o * PLO]        = acc[oj].x * rcp_(acc[oj].y + EPSF) + bias[o];
      out[OUT1 + obase + o * PLO] = acc[oj].y * invCW;
    }
  }
}

// ---------------------------------------------------------------------------
extern "C" void kernel_launch(void* const* d_in, const int* in_sizes, int n_in,
                              void* d_out, int out_size, void* d_ws, size_t ws_size,
                              hipStream_t stream) {
  const float* d      = (const float*)d_in[0];
  const float* cd     = (const float*)d_in[1];
  const float* s      = (const float*)d_in[2];
  // d_in[3]=cs, d_in[4]=gx, d_in[5]=cgx unused by the reference
  const float* gy     = (const float*)d_in[6];
  const float* cgy    = (const float*)d_in[7];
  const float* spr    = (const float*)d_in[8];
  const float* w_prop = (const float*)d_in[9];
  const float* spw    = (const float*)d_in[10];
  const float* chw    = (const float*)d_in[11];
  const float* bias   = (const float*)d_in[12];
  float* out = (float*)d_out;

  float* params = (float*)d_ws;                       // 4096 floats reserved
  unsigned* I   = (unsigned*)d_ws + 4096;             // packed bf16 intermediate (33.5 MB)

  // K1 (+1 setup block folded in, runs concurrently with streaming blocks)
  k1_gyf<<<NB1 + 1, 256, 0, stream>>>(d, cd, s, gy, cgy, w_prop, spw, chw, params, I);

  dim3 g2(4, HO, B_);   // (4, 254, 2) = 2032 blocks x 512 threads
  k2_fused<<<g2, 512, 0, stream>>>(I, spr, params, bias, out);
}

// Round 9
// 136.105 us; speedup vs baseline: 1.4646x; 1.0060x over previous
//
#include <hip/hip_runtime.h>

#define EPSF 1e-20f

typedef float v2f __attribute__((ext_vector_type(2)));
typedef float v4f __attribute__((ext_vector_type(4)));

constexpr int B_ = 2, C_ = 32, O_ = 32, H_ = 256, W_ = 512;
constexpr int HO = 254, WO = 510;
constexpr int HW  = H_ * W_;        // 131072
constexpr int PLO = HO * WO;        // 129540
constexpr int OUT1 = B_ * O_ * PLO;
constexpr int IMG  = B_ * C_ * HW;  // 8,388,608
constexpr int WT2  = 128;           // K2 tile width (pixels per block)
constexpr int NB1  = IMG / 4 / 256; // 8192 streaming blocks in K1

__device__ __forceinline__ float sp_(float x) { return log1pf(expf(x)); }
__device__ __forceinline__ float rcp_(float x) { return __builtin_amdgcn_rcpf(x); }

// pack two floats as bf16(RN) into one uint: low16 = P, high16 = Q
__device__ __forceinline__ unsigned bfpack(float g, float c) {
  unsigned ug = __float_as_uint(g);
  unsigned uc = __float_as_uint(c);
  ug = ug + 0x7FFFu + ((ug >> 16) & 1u);
  uc = uc + 0x7FFFu + ((uc >> 16) & 1u);
  return (ug >> 16) | (uc & 0xFFFF0000u);
}
__device__ __forceinline__ float bf_lo(unsigned u) { return __uint_as_float(u << 16); }
__device__ __forceinline__ float bf_hi(unsigned u) { return __uint_as_float(u & 0xFFFF0000u); }

// ---------------------------------------------------------------------------
// K1: per-pixel vertical fusion -> packed bf16 (P, Q) where
//   P = gy_f * cgy_f = (a*gy + cfd*gfd) / (w+1)     [the (a+cfd) div cancels]
//   Q = cgy_f        = (a + cfd) / (w+1)
// This is exactly what K2's conv needs: nom = sum spv*sw*P, den = sum spv*sw*Q.
// Block NB1 (extra last block) performs the weight setup concurrently:
//   params: [0]=w [1]=sum(sw) [2]=sum(cw) [16..304)=sw[c][k] [304..1328)=cwT[c][o]
// ---------------------------------------------------------------------------
__global__ __launch_bounds__(256) void k1_gyf(const float* __restrict__ d,
                                              const float* __restrict__ cd,
                                              const float* __restrict__ s,
                                              const float* __restrict__ gy,
                                              const float* __restrict__ cgy,
                                              const float* __restrict__ w_prop,
                                              const float* __restrict__ spw,
                                              const float* __restrict__ chw,
                                              float* __restrict__ params,
                                              unsigned* __restrict__ I) {
  __shared__ float red[256];
  const int t = threadIdx.x;

  if (blockIdx.x == NB1) {            // ---- setup block ----
    float l1 = 0.f;
    for (int i = t; i < 288; i += 256) { float v = sp_(spw[i]); params[16 + i] = v; l1 += v; }
    red[t] = l1; __syncthreads();
    for (int k = 128; k > 0; k >>= 1) { if (t < k) red[t] += red[t + k]; __syncthreads(); }
    float SW = red[0]; __syncthreads();
    float l2 = 0.f;
    for (int i = t; i < 1024; i += 256) {
      int o = i >> 5, c = i & 31;
      float v = sp_(chw[o * C_ + c]);
      params[304 + c * O_ + o] = v;   // transposed store
      l2 += v;
    }
    red[t] = l2; __syncthreads();
    for (int k = 128; k > 0; k >>= 1) { if (t < k) red[t] += red[t + k]; __syncthreads(); }
    if (t == 0) { params[0] = sp_(w_prop[0]); params[1] = SW; params[2] = red[0]; }
    return;
  }

  const float w      = sp_(w_prop[0]);   // computed inline (no params dependency)
  const float inv_w1 = rcp_(w + 1.0f);
  const int idx = blockIdx.x * 256 + t;
  const long i4 = (long)idx * 4;
  const int h = (int)((i4 >> 9) & (H_ - 1));
  const long up = (h == 0)      ? i4 + (long)(H_ - 1) * W_ : i4 - W_;
  const long dn = (h == H_ - 1) ? i4 - (long)(H_ - 1) * W_ : i4 + W_;

  float4 duv = *(const float4*)(d + up);
  float4 ddv = *(const float4*)(d + dn);
  float4 sv  = *(const float4*)(s + i4);
  float4 suv = *(const float4*)(s + up);
  float4 sdv = *(const float4*)(s + dn);
  float4 cduv = (h == 0)      ? make_float4(0.f, 0.f, 0.f, 0.f) : *(const float4*)(cd + up);
  float4 cddv = (h == H_ - 1) ? make_float4(0.f, 0.f, 0.f, 0.f) : *(const float4*)(cd + dn);
  float4 gyv  = *(const float4*)(gy + i4);
  float4 cgyv = *(const float4*)(cgy + i4);

  const float* pdu = (const float*)&duv;  const float* pdd = (const float*)&ddv;
  const float* ps  = (const float*)&sv;   const float* psu = (const float*)&suv;
  const float* psd = (const float*)&sdv;  const float* pcu = (const float*)&cduv;
  const float* pcd = (const float*)&cddv; const float* pg  = (const float*)&gyv;
  const float* pc  = (const float*)&cgyv;

  uint4 o;
  unsigned* po = (unsigned*)&o;
#pragma unroll
  for (int j = 0; j < 4; ++j) {
    const float cu = pcu[j], cdn = pcd[j];
    const float cfd = ps[j] * psu[j] * psd[j] * cu * cu;           // cd_up twice (faithful)
    const float height = (cu * pdu[j] + cdn * pdd[j]) * rcp_(cu + cdn + EPSF);
    const float gfd = (pdd[j] - pdu[j]) * 0.5f * rcp_(height + EPSF);
    const float a = w * pc[j];
    const float P = (a * pg[j] + cfd * gfd) * inv_w1;   // gy_f * cgy_f (div cancels)
    const float Q = (a + cfd) * inv_w1;                 // cgy_f
    po[j] = bfpack(P, Q);
  }
  *(uint4*)(I + i4) = o;
}

// ---------------------------------------------------------------------------
// K2: fused 3x3 grouped conv + 1x1 channel mix. 512 threads, 128-px tile.
// Phase A: wave = channel-group of 4 (cg = t>>6 wave-uniform), lane = px-pair;
//          512B wave-contiguous loads; 3 packed ops per tap:
//          t = spv*sw; nom += t*P; den += t*Q. sw via wave-uniform s_loads.
//          AB = (nom*invSW, den*invSW) = (gy_sp*cgy_sp, cgy_sp), eps folded.
// Phase B: px = t&127, o-group = t>>7 (wave-uniform); ds_read_b64 +
//          v_pk_fma channel mix; weights via wave-uniform s_loads.
// ---------------------------------------------------------------------------
__global__ __launch_bounds__(512) void k2_fused(const unsigned* __restrict__ I,
                                                const float* __restrict__ spr,
                                                const float* __restrict__ params,
                                                const float* __restrict__ bias,
                                                float* __restrict__ out) {
  __shared__ v2f AB[C_][WT2 + 2];   // [c][px], pad 2 -> 130 v2f per row (1040B, 16B-aligned)

  const int b   = blockIdx.z;
  const int ho  = blockIdx.y;
  const int wo0 = blockIdx.x * WT2;
  const int t   = threadIdx.x;

  const float invSW = rcp_(params[1]);
  const float invCW = rcp_(params[2]);

  // ---- Phase A ----
  const int pp = t & 63;                                     // pixel pair: px = 2pp, 2pp+1
  const int cg = __builtin_amdgcn_readfirstlane(t >> 6);     // 0..7, wave-uniform
  const int wo  = wo0 + 2 * pp;
  const int wos = (wo <= WO - 2) ? wo : (WO - 2);            // even clamp (508)

#pragma unroll
  for (int ci = 0; ci < 4; ++ci) {
    const int c = cg * 4 + ci;
    const unsigned* Ip = I + (b * C_ + c) * HW + ho * W_ + wos;
    uint2 r0a = *(const uint2*)(Ip);
    uint2 r0b = *(const uint2*)(Ip + 2);
    uint2 r1a = *(const uint2*)(Ip + W_);
    uint2 r1b = *(const uint2*)(Ip + W_ + 2);
    uint2 r2a = *(const uint2*)(Ip + 2 * W_);
    uint2 r2b = *(const uint2*)(Ip + 2 * W_ + 2);

    const float* sp = spr + (long)(b * C_ + c) * 9 * PLO + ho * WO + wos;
    v2f spv[9];
#pragma unroll
    for (int k = 0; k < 9; ++k) spv[k] = *(const v2f*)(sp + (long)k * PLO);

    unsigned urow[3][4] = {{r0a.x, r0a.y, r0b.x, r0b.y},
                           {r1a.x, r1a.y, r1b.x, r1b.y},
                           {r2a.x, r2a.y, r2b.x, r2b.y}};
    float P[3][4], Q[3][4];
#pragma unroll
    for (int i = 0; i < 3; ++i)
#pragma unroll
      for (int j = 0; j < 4; ++j) { P[i][j] = bf_lo(urow[i][j]); Q[i][j] = bf_hi(urow[i][j]); }

    const float* swc = params + 16 + c * 9;   // wave-uniform -> s_load
    v2f nom = (v2f){0.f, 0.f};
    v2f den = (v2f){0.f, 0.f};
#pragma unroll
    for (int i = 0; i < 3; ++i) {
#pragma unroll
      for (int j = 0; j < 3; ++j) {
        const v2f tk = spv[i * 3 + j] * swc[i * 3 + j];           // pk_mul
        nom += tk * (v2f){P[i][j], P[i][j + 1]};                  // pk_fma
        den += tk * (v2f){Q[i][j], Q[i][j + 1]};                  // pk_fma
      }
    }
    // single b128 store: (px0.g, px0.c, px1.g, px1.c)
    *(v4f*)&AB[c][2 * pp] = (v4f){nom.x * invSW, den.x * invSW,
                                  nom.y * invSW, den.y * invSW};
  }
  __syncthreads();

  // ---- Phase B ----
  const int px  = t & 127;
  const int og  = __builtin_amdgcn_readfirstlane(t >> 7);  // 0..3, wave-uniform
  const int wob = wo0 + px;

  v2f ab[C_];
#pragma unroll
  for (int c = 0; c < C_; ++c) ab[c] = AB[c][px];

  const float* cwT = params + 304;     // [c][o], uniform indices -> s_load
  v2f acc[8];
#pragma unroll
  for (int oj = 0; oj < 8; ++oj) acc[oj] = (v2f){0.f, 0.f};
#pragma unroll
  for (int c = 0; c < C_; ++c) {
#pragma unroll
    for (int oj = 0; oj < 8; ++oj)
      acc[oj] += ab[c] * cwT[c * O_ + og * 8 + oj];   // v_pk_fma_f32
  }

  if (wob < WO) {
    const int obase = b * O_ * PLO + ho * WO + wob;
#pragma unroll
    for (int oj = 0; oj < 8; ++oj) {
      const int o = og * 8 + oj;
      out[obase + o * PLO]        = acc[oj].x * rcp_(acc[oj].y + EPSF) + bias[o];
      out[OUT1 + obase + o * PLO] = acc[oj].y * invCW;
    }
  }
}

// ---------------------------------------------------------------------------
extern "C" void kernel_launch(void* const* d_in, const int* in_sizes, int n_in,
                              void* d_out, int out_size, void* d_ws, size_t ws_size,
                              hipStream_t stream) {
  const float* d      = (const float*)d_in[0];
  const float* cd     = (const float*)d_in[1];
  const float* s      = (const float*)d_in[2];
  // d_in[3]=cs, d_in[4]=gx, d_in[5]=cgx unused by the reference
  const float* gy     = (const float*)d_in[6];
  const float* cgy    = (const float*)d_in[7];
  const float* spr    = (const float*)d_in[8];
  const float* w_prop = (const float*)d_in[9];
  const float* spw    = (const float*)d_in[10];
  const float* chw    = (const float*)d_in[11];
  const float* bias   = (const float*)d_in[12];
  float* out = (float*)d_out;

  float* params = (float*)d_ws;                       // 4096 floats reserved
  unsigned* I   = (unsigned*)d_ws + 4096;             // packed bf16 intermediate (33.5 MB)

  // K1 (+1 setup block folded in, runs concurrently with streaming blocks)
  k1_gyf<<<NB1 + 1, 256, 0, stream>>>(d, cd, s, gy, cgy, w_prop, spw, chw, params, I);

  dim3 g2(4, HO, B_);   // (4, 254, 2) = 2032 blocks x 512 threads
  k2_fused<<<g2, 512, 0, stream>>>(I, spr, params, bias, out);
}